// Round 7
// baseline (15.167 us; speedup 1.0000x reference)
//
#include <hip/hip_runtime.h>
#include <cfloat>

// TripletSemiHardLoss — B=512, D=128, scalar f32 out.
// R7: single kernel. R6 compute (DPP reduces, coalesced dot, ballot mining)
// + fence-free completion protocol:
//  - per-block results published via per-access scoped atomics
//    (__hip_atomic_store RELAXED/AGENT = write-through; no threadfence,
//     no L2 writeback — R3's 40us mistake was 2048 wave-level fences)
//  - signal via atomicInc(done,255) wrap trick: correct for ANY initial
//    value >= 255 (harness poison 0xAAAAAAAA ✓); last block restores
//    0x40000000 so every graph replay behaves identically.
//  - last arriver (old==254) reduces 512 partials with scoped loads
//    (sc-bit L2 bypass -> coherence point) in one wave. No spinning.

constexpr int   BN       = 512;
constexpr int   DD       = 128;
constexpr float MARGIN_F = 0.1f;
constexpr int   NBLK     = BN / 2;   // 256 blocks, 2 anchors each

template <int CTRL>
__device__ inline float dppAdd(float v) {
    int x = __builtin_amdgcn_update_dpp(__float_as_int(v), __float_as_int(v),
                                        CTRL, 0xF, 0xF, false);
    return v + __int_as_float(x);
}
template <int CTRL>
__device__ inline float dppMin(float v) {
    int x = __builtin_amdgcn_update_dpp(__float_as_int(v), __float_as_int(v),
                                        CTRL, 0xF, 0xF, false);
    return fminf(v, __int_as_float(x));
}
template <int CTRL>
__device__ inline float dppMax(float v) {
    int x = __builtin_amdgcn_update_dpp(__float_as_int(v), __float_as_int(v),
                                        CTRL, 0xF, 0xF, false);
    return fmaxf(v, __int_as_float(x));
}
constexpr int DPP_XOR1 = 0xB1;   // quad_perm [1,0,3,2]
constexpr int DPP_XOR2 = 0x4E;   // quad_perm [2,3,0,1]
constexpr int DPP_ROR4 = 0x124;  // row_ror:4
constexpr int DPP_ROR8 = 0x128;  // row_ror:8

__device__ inline float waveMin64(float v) {
    v = dppMin<DPP_XOR1>(v);
    v = dppMin<DPP_XOR2>(v);
    v = dppMin<DPP_ROR4>(v);
    v = dppMin<DPP_ROR8>(v);
    v = fminf(v, __shfl_xor(v, 16, 64));
    v = fminf(v, __shfl_xor(v, 32, 64));
    return v;
}
__device__ inline float waveMax64(float v) {
    v = dppMax<DPP_XOR1>(v);
    v = dppMax<DPP_XOR2>(v);
    v = dppMax<DPP_ROR4>(v);
    v = dppMax<DPP_ROR8>(v);
    v = fmaxf(v, __shfl_xor(v, 16, 64));
    v = fmaxf(v, __shfl_xor(v, 32, 64));
    return v;
}

__global__ __launch_bounds__(512) void triplet_fused(
    const float* __restrict__ emb, const int* __restrict__ labels,
    float* __restrict__ loss_part, int* __restrict__ cnt_part,
    unsigned* __restrict__ done, float* __restrict__ out)
{
    __shared__ __align__(16) float ej0[DD];
    __shared__ __align__(16) float ej1[DD];
    __shared__ __align__(16) float dist0[BN];
    __shared__ __align__(16) float dist1[BN];
    __shared__ float wsum8[8];
    __shared__ int   nposs[2];
    __shared__ unsigned islast;

    const int t    = threadIdx.x;
    const int w    = t >> 6;
    const int lane = t & 63;
    const int sub  = t & 3;     // 4 lanes per row
    const int a0   = blockIdx.x * 2;
    const int a1   = a0 + 1;

    // stage anchor embeddings
    if (t < DD)          ej0[t]      = emb[(size_t)a0 * DD + t];
    else if (t < 2 * DD) ej1[t - DD] = emb[(size_t)a1 * DD + (t - DD)];
    __syncthreads();

    // preload this thread's anchor fragments
    float4 e0q[8], e1q[8];
    {
        const float4* ej0v = reinterpret_cast<const float4*>(ej0);
        const float4* ej1v = reinterpret_cast<const float4*>(ej1);
#pragma unroll
        for (int qq = 0; qq < 8; ++qq) {
            e0q[qq] = ej0v[qq * 4 + sub];
            e1q[qq] = ej1v[qq * 4 + sub];
        }
    }

    // dot pass: 4 passes x 128 rows, 4 lanes per row (64B/quad contiguous)
    const int rbase = t >> 2;   // 0..127
#pragma unroll 2
    for (int pass = 0; pass < 4; ++pass) {
        const int r = pass * 128 + rbase;
        const float4* rowv = reinterpret_cast<const float4*>(emb + (size_t)r * DD);
        float d0 = 0.f, d1 = 0.f;
#pragma unroll
        for (int qq = 0; qq < 8; ++qq) {
            const float4 b = rowv[qq * 4 + sub];
            const float4 A = e0q[qq], C = e1q[qq];
            d0 += A.x * b.x + A.y * b.y + A.z * b.z + A.w * b.w;
            d1 += C.x * b.x + C.y * b.y + C.z * b.z + C.w * b.w;
        }
        d0 = dppAdd<DPP_XOR1>(d0);
        d0 = dppAdd<DPP_XOR2>(d0);
        d1 = dppAdd<DPP_XOR1>(d1);
        d1 = dppAdd<DPP_XOR2>(d1);
        // unit-norm rows: dist = max(2 - 2*dot, 0); zero diagonal inline
        if (sub == 0) {
            const float dd = fmaxf(2.f - 2.f * d0, 0.f);
            dist0[r] = (r == a0) ? 0.f : dd;
        } else if (sub == 1) {
            const float dd = fmaxf(2.f - 2.f * d1, 0.f);
            dist1[r] = (r == a1) ? 0.f : dd;
        }
    }
    __syncthreads();

    // --- mining: waves 0-3 -> anchor a0, waves 4-7 -> anchor a1 ---
    const int    A     = (w < 4) ? a0 : a1;
    const int    wi    = w & 3;
    const float* distA = (w < 4) ? dist0 : dist1;

    const float4* dv  = reinterpret_cast<const float4*>(distA) + lane * 2;
    const float4  dA4 = dv[0], dB4 = dv[1];
    const int4*   lv  = reinterpret_cast<const int4*>(labels) + lane * 2;
    const int4    lA4 = lv[0], lB4 = lv[1];
    const float ddv[8] = {dA4.x, dA4.y, dA4.z, dA4.w, dB4.x, dB4.y, dB4.z, dB4.w};
    const int   llv[8] = {lA4.x, lA4.y, lA4.z, lA4.w, lB4.x, lB4.y, lB4.z, lB4.w};
    const int   labA   = labels[A];

    float dn[8];
    float nmax = 0.f;
#pragma unroll
    for (int q = 0; q < 8; ++q) {
        const bool neg = (llv[q] != labA);
        dn[q] = neg ? ddv[q] : FLT_MAX;
        nmax  = neg ? fmaxf(nmax, ddv[q]) : nmax;
    }
    const float neg_inside = waveMax64(nmax);

    int   npos = 0;
    int   p    = 0;
    float wsum = 0.f;
#pragma unroll
    for (int q = 0; q < 8; ++q) {
        unsigned long long m = __ballot((llv[q] == labA) && (lane * 8 + q != A));
        npos += __popcll(m);
        while (m) {
            const int src = __ffsll((long long)m) - 1;
            m &= m - 1;
            if ((p & 3) == wi) {                       // wave-uniform
                const float dpos = __shfl(ddv[q], src, 64);
                float mn = FLT_MAX;
#pragma unroll
                for (int qq = 0; qq < 8; ++qq)
                    mn = fminf(mn, (dn[qq] > dpos) ? dn[qq] : FLT_MAX);
                mn = waveMin64(mn);
                const float shn = (mn < FLT_MAX) ? mn : neg_inside;
                wsum += fmaxf(MARGIN_F + dpos - shn, 0.f);
            }
            ++p;
        }
    }
    if (lane == 0) wsum8[w] = wsum;
    if (lane == 1 && w == 0) nposs[0] = npos;
    if (lane == 1 && w == 4) nposs[1] = npos;
    __syncthreads();

    // --- publish + signal (t0 only; no fences, scoped write-through) ---
    if (t == 0) {
        const float L0 = (wsum8[0] + wsum8[1]) + (wsum8[2] + wsum8[3]);
        const float L1 = (wsum8[4] + wsum8[5]) + (wsum8[6] + wsum8[7]);
        __hip_atomic_store(&loss_part[a0], L0, __ATOMIC_RELAXED,
                           __HIP_MEMORY_SCOPE_AGENT);
        __hip_atomic_store(&loss_part[a1], L1, __ATOMIC_RELAXED,
                           __HIP_MEMORY_SCOPE_AGENT);
        __hip_atomic_store(&cnt_part[blockIdx.x], nposs[0] + nposs[1],
                           __ATOMIC_RELAXED, __HIP_MEMORY_SCOPE_AGENT);
        asm volatile("s_waitcnt vmcnt(0)" ::: "memory");  // drain before signal
        const unsigned old = atomicInc(done, 255u);       // wrap: any init>=255 ok
        islast = (old == (unsigned)(NBLK - 2)) ? 1u : 0u; // 256th arriver
    }
    __syncthreads();

    // --- last arriver: one-wave reduction over scoped (coherent) loads ---
    if (islast && w == 0) {
        float s = 0.f;
        int   c = 0;
#pragma unroll
        for (int q = 0; q < 8; ++q)
            s += __hip_atomic_load(&loss_part[lane * 8 + q], __ATOMIC_RELAXED,
                                   __HIP_MEMORY_SCOPE_AGENT);
#pragma unroll
        for (int q = 0; q < 4; ++q)
            c += __hip_atomic_load(&cnt_part[lane * 4 + q], __ATOMIC_RELAXED,
                                   __HIP_MEMORY_SCOPE_AGENT);
#pragma unroll
        for (int o = 1; o < 64; o <<= 1) {
            s += __shfl_xor(s, o, 64);
            c += __shfl_xor(c, o, 64);
        }
        if (lane == 0) {
            out[0] = s / (float)c;
            // restore counter to a value >= 255 so next replay wraps identically
            __hip_atomic_store(done, 0x40000000u, __ATOMIC_RELAXED,
                               __HIP_MEMORY_SCOPE_AGENT);
        }
    }
}

extern "C" void kernel_launch(void* const* d_in, const int* in_sizes, int n_in,
                              void* d_out, int out_size, void* d_ws, size_t ws_size,
                              hipStream_t stream)
{
    const float* emb    = (const float*)d_in[0];
    const int*   labels = (const int*)d_in[1];
    float*       out    = (float*)d_out;

    float*    loss_part = (float*)d_ws;
    int*      cnt_part  = (int*)((char*)d_ws + BN * sizeof(float));
    unsigned* done      = (unsigned*)((char*)d_ws + BN * sizeof(float)
                                      + NBLK * sizeof(int));

    triplet_fused<<<NBLK, 512, 0, stream>>>(emb, labels, loss_part, cnt_part,
                                            done, out);
}

// Round 8
// 14.350 us; speedup vs baseline: 1.0569x; 1.0569x over previous
//
#include <hip/hip_runtime.h>
#include <cfloat>

// TripletSemiHardLoss — B=512, D=128, scalar f32 out.
// R8: two kernels (R6 protocol — R7's in-kernel completion was a net tail).
// Anchor latency fixes:
//  - 1024 threads/block (16 waves -> 4/SIMD, 2x latency hiding vs R6)
//  - anchor fragments loaded direct from global (L1-resident; staging
//    phase + one barrier removed)
//  - dot: 2 passes x 256 rows, 4 lanes/row, DPP quad_perm reduce (VALU pipe)
//  - mining: 8 waves/anchor, ballot in-register, readlane broadcast
//    (wave-uniform src -> SALU, off the LDS pipe)
// Finalize: 1-wave fixed-order reduce (deterministic).

constexpr int   BN       = 512;
constexpr int   DD       = 128;
constexpr float MARGIN_F = 0.1f;
constexpr int   NBLK     = BN / 2;   // 256 blocks, 2 anchors each

template <int CTRL>
__device__ inline float dppAdd(float v) {
    int x = __builtin_amdgcn_update_dpp(__float_as_int(v), __float_as_int(v),
                                        CTRL, 0xF, 0xF, false);
    return v + __int_as_float(x);
}
template <int CTRL>
__device__ inline float dppMin(float v) {
    int x = __builtin_amdgcn_update_dpp(__float_as_int(v), __float_as_int(v),
                                        CTRL, 0xF, 0xF, false);
    return fminf(v, __int_as_float(x));
}
template <int CTRL>
__device__ inline float dppMax(float v) {
    int x = __builtin_amdgcn_update_dpp(__float_as_int(v), __float_as_int(v),
                                        CTRL, 0xF, 0xF, false);
    return fmaxf(v, __int_as_float(x));
}
constexpr int DPP_XOR1 = 0xB1;   // quad_perm [1,0,3,2]
constexpr int DPP_XOR2 = 0x4E;   // quad_perm [2,3,0,1]
constexpr int DPP_ROR4 = 0x124;  // row_ror:4
constexpr int DPP_ROR8 = 0x128;  // row_ror:8

__device__ inline float waveMin64(float v) {
    v = dppMin<DPP_XOR1>(v);
    v = dppMin<DPP_XOR2>(v);
    v = dppMin<DPP_ROR4>(v);
    v = dppMin<DPP_ROR8>(v);
    v = fminf(v, __shfl_xor(v, 16, 64));
    v = fminf(v, __shfl_xor(v, 32, 64));
    return v;
}
__device__ inline float waveMax64(float v) {
    v = dppMax<DPP_XOR1>(v);
    v = dppMax<DPP_XOR2>(v);
    v = dppMax<DPP_ROR4>(v);
    v = dppMax<DPP_ROR8>(v);
    v = fmaxf(v, __shfl_xor(v, 16, 64));
    v = fmaxf(v, __shfl_xor(v, 32, 64));
    return v;
}

__global__ __launch_bounds__(1024) void triplet_anchor(
    const float* __restrict__ emb, const int* __restrict__ labels,
    float* __restrict__ loss_part, int* __restrict__ cnt_part)
{
    __shared__ __align__(16) float dist0[BN];
    __shared__ __align__(16) float dist1[BN];
    __shared__ float wsum16[16];

    const int t    = threadIdx.x;
    const int w    = t >> 6;     // 0..15
    const int lane = t & 63;
    const int sub  = t & 3;      // 4 lanes per row
    const int a0   = blockIdx.x * 2;
    const int a1   = a0 + 1;

    // anchor fragments direct from global (1 KB, L1-resident after wave 0)
    float4 e0q[8], e1q[8];
    {
        const float4* e0v = reinterpret_cast<const float4*>(emb + (size_t)a0 * DD);
        const float4* e1v = reinterpret_cast<const float4*>(emb + (size_t)a1 * DD);
#pragma unroll
        for (int qq = 0; qq < 8; ++qq) {
            e0q[qq] = e0v[qq * 4 + sub];
            e1q[qq] = e1v[qq * 4 + sub];
        }
    }

    // dot pass: 2 passes x 256 rows, 4 lanes per row (64B/quad contiguous)
    const int rbase = t >> 2;    // 0..255
#pragma unroll
    for (int pass = 0; pass < 2; ++pass) {
        const int r = pass * 256 + rbase;
        const float4* rowv = reinterpret_cast<const float4*>(emb + (size_t)r * DD);
        float d0 = 0.f, d1 = 0.f;
#pragma unroll
        for (int qq = 0; qq < 8; ++qq) {
            const float4 b = rowv[qq * 4 + sub];
            const float4 A = e0q[qq], C = e1q[qq];
            d0 += A.x * b.x + A.y * b.y + A.z * b.z + A.w * b.w;
            d1 += C.x * b.x + C.y * b.y + C.z * b.z + C.w * b.w;
        }
        d0 = dppAdd<DPP_XOR1>(d0);
        d0 = dppAdd<DPP_XOR2>(d0);
        d1 = dppAdd<DPP_XOR1>(d1);
        d1 = dppAdd<DPP_XOR2>(d1);
        // unit-norm rows: dist = max(2 - 2*dot, 0); zero diagonal inline
        if (sub == 0) {
            const float dd = fmaxf(2.f - 2.f * d0, 0.f);
            dist0[r] = (r == a0) ? 0.f : dd;
        } else if (sub == 1) {
            const float dd = fmaxf(2.f - 2.f * d1, 0.f);
            dist1[r] = (r == a1) ? 0.f : dd;
        }
    }
    __syncthreads();

    // --- mining: waves 0-7 -> anchor a0, waves 8-15 -> anchor a1 ---
    const int    A     = (w < 8) ? a0 : a1;
    const int    wi    = w & 7;
    const float* distA = (w < 8) ? dist0 : dist1;

    const float4* dv  = reinterpret_cast<const float4*>(distA) + lane * 2;
    const float4  dA4 = dv[0], dB4 = dv[1];
    const int4*   lv  = reinterpret_cast<const int4*>(labels) + lane * 2;
    const int4    lA4 = lv[0], lB4 = lv[1];
    const float ddv[8] = {dA4.x, dA4.y, dA4.z, dA4.w, dB4.x, dB4.y, dB4.z, dB4.w};
    const int   llv[8] = {lA4.x, lA4.y, lA4.z, lA4.w, lB4.x, lB4.y, lB4.z, lB4.w};
    const int   labA   = labels[A];

    float dn[8];
    float nmax = 0.f;
#pragma unroll
    for (int q = 0; q < 8; ++q) {
        const bool neg = (llv[q] != labA);
        dn[q] = neg ? ddv[q] : FLT_MAX;
        nmax  = neg ? fmaxf(nmax, ddv[q]) : nmax;
    }
    const float neg_inside = waveMax64(nmax);

    int   npos = 0;
    int   p    = 0;
    float wsum = 0.f;
#pragma unroll
    for (int q = 0; q < 8; ++q) {
        unsigned long long m = __ballot((llv[q] == labA) && (lane * 8 + q != A));
        npos += __popcll(m);
        while (m) {
            const int src = __ffsll((long long)m) - 1;   // wave-uniform
            m &= m - 1;
            if ((p & 7) == wi) {
                const float dpos = __int_as_float(
                    __builtin_amdgcn_readlane(__float_as_int(ddv[q]), src));
                float mn = FLT_MAX;
#pragma unroll
                for (int qq = 0; qq < 8; ++qq)
                    mn = fminf(mn, (dn[qq] > dpos) ? dn[qq] : FLT_MAX);
                mn = waveMin64(mn);
                const float shn = (mn < FLT_MAX) ? mn : neg_inside;
                wsum += fmaxf(MARGIN_F + dpos - shn, 0.f);
            }
            ++p;
        }
    }
    if (lane == 0) wsum16[w] = wsum;
    if (lane == 1 && (w == 0 || w == 8)) cnt_part[A] = npos;
    __syncthreads();
    if (t == 0)
        loss_part[a0] = ((wsum16[0] + wsum16[1]) + (wsum16[2] + wsum16[3]))
                      + ((wsum16[4] + wsum16[5]) + (wsum16[6] + wsum16[7]));
    if (t == 1)
        loss_part[a1] = ((wsum16[8] + wsum16[9]) + (wsum16[10] + wsum16[11]))
                      + ((wsum16[12] + wsum16[13]) + (wsum16[14] + wsum16[15]));
}

__global__ __launch_bounds__(64) void triplet_finalize(
    const float* __restrict__ loss_part, const int* __restrict__ cnt_part,
    float* __restrict__ out)
{
    const int t = threadIdx.x;   // one wave
    const float4* lp = reinterpret_cast<const float4*>(loss_part);
    const int4*   cp = reinterpret_cast<const int4*>(cnt_part);
    const float4 s0 = lp[t], s1 = lp[t + 64];
    const int4   c0 = cp[t], c1 = cp[t + 64];
    float s = ((s0.x + s0.y) + (s0.z + s0.w)) + ((s1.x + s1.y) + (s1.z + s1.w));
    int   c = (c0.x + c0.y + c0.z + c0.w) + (c1.x + c1.y + c1.z + c1.w);
#pragma unroll
    for (int o = 1; o < 64; o <<= 1) {
        s += __shfl_xor(s, o, 64);
        c += __shfl_xor(c, o, 64);
    }
    if (t == 0) out[0] = s / (float)c;
}

extern "C" void kernel_launch(void* const* d_in, const int* in_sizes, int n_in,
                              void* d_out, int out_size, void* d_ws, size_t ws_size,
                              hipStream_t stream)
{
    const float* emb    = (const float*)d_in[0];
    const int*   labels = (const int*)d_in[1];
    float*       out    = (float*)d_out;

    float* loss_part = (float*)d_ws;
    int*   cnt_part  = (int*)((char*)d_ws + BN * sizeof(float));

    triplet_anchor<<<NBLK, 1024, 0, stream>>>(emb, labels, loss_part, cnt_part);
    triplet_finalize<<<1, 64, 0, stream>>>(loss_part, cnt_part, out);
}